// Round 3
// baseline (61.501 us; speedup 1.0000x reference)
//
#include <hip/hip_runtime.h>

// GlobalConvolutionalLayer: out[n,c,m] = 0.5*xi_eff[c]*dx * sum_l d[n,l]*exp(-|x_l-x_m|*xi_eff[c])
// Separable exponential kernel on a sorted uniform grid:
//   out[m] = scale * ( e^{-x_m k} * A_m + e^{+x_m k} * B_m )
//   A_m = sum_{l<=m} d[l] e^{+x_l k},  B_m = sum_{l>m} d[l] e^{-x_l k}
// xi_eff = 1/sigmoid(xi) = 1 + exp(-xi) in (1.37, 2]; |x*k| <= 2, no overflow.
//
// v3 (re-run; previous bench died to a container infra failure, not the kernel):
// ONE dispatch (v2's two-phase cost ~7us extra in dispatch gap). 512 blocks
// = 32 (n,c) combos x 16 segments -> 2 blocks/CU across all 256 CUs. Each block
// recomputes the cross-segment offsets from the L1-resident density row
// (redundant expf is ~1us chip-wide, cheaper than a second dependent launch),
// then scans only its own 256-element segment.

#define GG 4096
#define CC 8
#define NN 4
#define SS 16               // segments per (n,c) scan
#define SEG (GG / SS)       // 256 elements per segment = 1 per thread
#define BLOCK 256
#define NBLK (NN * CC * SS) // 512 blocks

__global__ __launch_bounds__(BLOCK) void gconv_one(const float* __restrict__ density,
                                                   const float* __restrict__ xi,
                                                   const float* __restrict__ grid,
                                                   float* __restrict__ out) {
    const int bid   = blockIdx.x;
    const int seg   = bid & (SS - 1);
    const int combo = bid >> 4;          // log2(SS)
    const int c     = combo & (CC - 1);
    const int n     = combo >> 3;        // log2(CC)
    const int tid   = threadIdx.x;
    const int lane  = tid & 63;
    const int wave  = tid >> 6;

    const float k     = 1.0f + __expf(-xi[c]);   // xi_eff = 1/sigmoid(xi)
    const float grid0 = grid[0];
    const float dx    = grid[1] - grid0;         // uniform spacing = 1/G
    const float* drow = density + n * GG;

    // Full row pass: strided so element l = i*SEG + tid; own-segment element is i==seg.
    // Branch conditions uniform in i -> no divergence.
    float offA = 0.0f, offB = 0.0f;              // per-thread partial of other-segment sums
    float mya = 0.0f, myb = 0.0f, myea = 1.0f, myeb = 1.0f;
#pragma unroll
    for (int i = 0; i < SS; ++i) {
        const int l   = i * SEG + tid;
        const float d = drow[l];                 // coalesced, L1/L2-resident (16 KB row)
        const float x = fmaf((float)l, dx, grid0);
        const float ep = __expf(x * k);
        const float em = __expf(-x * k);
        const float a = d * ep;
        const float b = d * em;
        if (i < seg)      offA += a;             // segments strictly before mine
        else if (i > seg) offB += b;             // segments strictly after mine
        else { mya = a; myb = b; myea = ep; myeb = em; }
    }

    // Block-wide reduce of offA/offB (exact cross-segment prefix/suffix sums).
    float rA = offA, rB = offB;
#pragma unroll
    for (int off = 32; off > 0; off >>= 1) {
        rA += __shfl_xor(rA, off, 64);
        rB += __shfl_xor(rB, off, 64);
    }
    __shared__ float sRA[BLOCK / 64], sRB[BLOCK / 64];
    if (lane == 0) { sRA[wave] = rA; sRB[wave] = rB; }
    __syncthreads();
    offA = sRA[0] + sRA[1] + sRA[2] + sRA[3];
    offB = sRB[0] + sRB[1] + sRB[2] + sRB[3];

    // Intra-segment: wave inclusive prefix of a, inclusive suffix of b.
    float pa = mya, sb = myb;
#pragma unroll
    for (int off = 1; off < 64; off <<= 1) {
        const float tA = __shfl_up(pa, off, 64);
        if (lane >= off) pa += tA;
        const float tB = __shfl_down(sb, off, 64);
        if (lane + off < 64) sb += tB;
    }

    // Cross-wave combine (4 waves). Distinct arrays -> no hazard with sRA/sRB reads.
    __shared__ float wTA[BLOCK / 64], wTB[BLOCK / 64];
    if (lane == 63) wTA[wave] = pa;   // wave total of a
    if (lane == 0)  wTB[wave] = sb;   // wave total of b
    __syncthreads();
    float wOffA = 0.0f, wOffB = 0.0f;
#pragma unroll
    for (int w = 0; w < BLOCK / 64; ++w) {
        if (w < wave) wOffA += wTA[w];
        if (w > wave) wOffB += wTB[w];
    }

    const float A = offA + wOffA + pa;          // sum_{l<=m} d[l] e^{+x_l k}
    const float B = offB + wOffB + (sb - myb);  // sum_{l>m}  d[l] e^{-x_l k}
    const float scale = 0.5f * k * dx;
    out[combo * GG + seg * SEG + tid] = scale * (myeb * A + myea * B);
}

extern "C" void kernel_launch(void* const* d_in, const int* in_sizes, int n_in,
                              void* d_out, int out_size, void* d_ws, size_t ws_size,
                              hipStream_t stream) {
    const float* density = (const float*)d_in[0];  // (N,1,G) fp32
    const float* xi      = (const float*)d_in[1];  // (C,)    fp32
    const float* grid    = (const float*)d_in[2];  // (G,)    fp32
    float* out           = (float*)d_out;          // (N,C,G) fp32

    gconv_one<<<NBLK, BLOCK, 0, stream>>>(density, xi, grid, out);
}

// Round 4
// 59.579 us; speedup vs baseline: 1.0323x; 1.0323x over previous
//
#include <hip/hip_runtime.h>

// GlobalConvolutionalLayer: out[n,c,m] = 0.5*xi_eff[c]*dx * sum_l d[n,l]*exp(-|x_l-x_m|*xi_eff[c])
// Separable exponential kernel on a sorted uniform grid -> prefix/suffix scans, O(G) per (n,c).
// xi_eff = 1/sigmoid(xi) = 1 + exp(-xi) in (1.37, 2]; exp(x*xi_eff) <= e^2, no overflow.
//
// v4 = v1 reverted (best measured: 58.5us, absmax 3.05e-5). Post-mortem of v2/v3:
// kernel exec is ~1-2us in ALL variants; dur_us is dominated by the harness's
// fixed per-iteration cost (256MB workspace poison fill ~40us at 85% HBM peak +
// ~16us of reset()/launch dispatch train). Restructuring to 512 blocks (v3) or
// two-phase (v2) moved measured totals only within session noise or worse.
// Keep the simplest single-dispatch form that measured best.

#define GG 4096
#define CC 8
#define NN 4
#define BLOCK 256
#define CHUNK (GG / BLOCK)  // 16 elements per thread

__global__ __launch_bounds__(BLOCK) void gconv_scan(const float* __restrict__ density,
                                                    const float* __restrict__ xi,
                                                    const float* __restrict__ grid,
                                                    float* __restrict__ out) {
    const int bid  = blockIdx.x;          // n*C + c  (matches output layout (N,C,G))
    const int c    = bid & (CC - 1);
    const int n    = bid >> 3;
    const int tid  = threadIdx.x;
    const int base = tid * CHUNK;

    const float k  = 1.0f + expf(-xi[c]); // xi_eff = 1/sigmoid(xi)
    const float dx = grid[1] - grid[0];   // uniform spacing = 1/G

    const float4* dv4 = reinterpret_cast<const float4*>(density + n * GG + base);
    const float4* gv4 = reinterpret_cast<const float4*>(grid + base);

    float ea[CHUNK];  // exp(+x*k)
    float eb[CHUNK];  // exp(-x*k)
    float pa[CHUNK];  // intra-chunk inclusive prefix of a[l] = d[l]*exp(+x_l*k)
    float sb[CHUNK];  // first b[l] = d[l]*exp(-x_l*k), then intra-chunk exclusive suffix

    float runA = 0.0f;
#pragma unroll
    for (int q = 0; q < CHUNK / 4; ++q) {
        float4 d4 = dv4[q];
        float4 g4 = gv4[q];
        float xs[4] = {g4.x, g4.y, g4.z, g4.w};
        float ds[4] = {d4.x, d4.y, d4.z, d4.w};
#pragma unroll
        for (int j = 0; j < 4; ++j) {
            const int i = q * 4 + j;
            const float e  = expf(xs[j] * k);
            const float ei = expf(-xs[j] * k);
            ea[i] = e;
            eb[i] = ei;
            runA += ds[j] * e;
            pa[i] = runA;
            sb[i] = ds[j] * ei;   // stash b value
        }
    }
    // intra-chunk exclusive suffix of b
    float runB = 0.0f;
#pragma unroll
    for (int i = CHUNK - 1; i >= 0; --i) {
        const float bv = sb[i];
        sb[i] = runB;
        runB += bv;
    }

    // wave-level (64-lane) inclusive scans of thread totals runA / runB
    float sA = runA, sB = runB;
#pragma unroll
    for (int off = 1; off < 64; off <<= 1) {
        const float tA = __shfl_up(sA, off, 64);
        const float tB = __shfl_up(sB, off, 64);
        if ((tid & 63) >= off) { sA += tA; sB += tB; }
    }

    __shared__ float wA[BLOCK / 64];
    __shared__ float wB[BLOCK / 64];
    const int wave = tid >> 6;
    if ((tid & 63) == 63) { wA[wave] = sA; wB[wave] = sB; }
    __syncthreads();

    float preA = 0.0f, preB = 0.0f, totB = 0.0f;
#pragma unroll
    for (int w = 0; w < BLOCK / 64; ++w) {
        const float ta = wA[w];
        const float tb = wB[w];
        if (w < wave) { preA += ta; preB += tb; }
        totB += tb;
    }
    const float offA = preA + (sA - runA);  // exclusive prefix across all threads
    const float offB = totB - (preB + sB);  // exclusive suffix across all threads

    const float scale = 0.5f * k * dx;
    float4* o4 = reinterpret_cast<float4*>(out + bid * GG + base);
#pragma unroll
    for (int q = 0; q < CHUNK / 4; ++q) {
        float4 r;
        float* rp = &r.x;
#pragma unroll
        for (int j = 0; j < 4; ++j) {
            const int i = q * 4 + j;
            const float A = offA + pa[i];     // sum_{l<=m} d[l]*e^{+x_l k}
            const float B = offB + sb[i];     // sum_{l> m} d[l]*e^{-x_l k}
            rp[j] = scale * (eb[i] * A + ea[i] * B);
        }
        o4[q] = r;
    }
}

extern "C" void kernel_launch(void* const* d_in, const int* in_sizes, int n_in,
                              void* d_out, int out_size, void* d_ws, size_t ws_size,
                              hipStream_t stream) {
    const float* density = (const float*)d_in[0];  // (N,1,G) fp32
    const float* xi      = (const float*)d_in[1];  // (C,)    fp32
    const float* grid    = (const float*)d_in[2];  // (G,)    fp32
    float* out           = (float*)d_out;          // (N,C,G) fp32

    gconv_scan<<<NN * CC, BLOCK, 0, stream>>>(density, xi, grid, out);
}